// Round 4
// baseline (253.170 us; speedup 1.0000x reference)
//
#include <hip/hip_runtime.h>
#include <hip/hip_bf16.h>

#define BB 2
#define SS 513
#define HH 512
#define NHH 8
#define DDIM 64

__device__ __forceinline__ float dot4(float4 a, float4 b) {
  return a.x * b.x + a.y * b.y + a.z * b.z + a.w * b.w;
}
__device__ __forceinline__ float4 add4(float4 a, float4 b) {
  return make_float4(a.x + b.x, a.y + b.y, a.z + b.z, a.w + b.w);
}

// ---------------------------------------------------------------------------
// Detect graph buffer layout: bool (1B/elem) vs int32/float32 (4B/elem).
__global__ __launch_bounds__(256) void detect_kernel(const uint4* __restrict__ gv,
                                                     int* __restrict__ flag) {
  __shared__ int s;
  if (threadIdx.x == 0) s = 0;
  __syncthreads();
  unsigned int local = 0;
  for (int i = threadIdx.x; i < 8192; i += 256) {  // 128 KB scan
    uint4 v = gv[i];
    local |= (v.x | v.y | v.z | v.w) & 0x0000ff00u;
  }
  if (local) atomicOr(&s, 1);
  __syncthreads();
  if (threadIdx.x == 0) *flag = s;
}

__device__ __forceinline__ bool graph_at(const void* g, int isBool, size_t idx) {
  if (isBool) return ((const unsigned char*)g)[idx] != 0;
  return ((const int*)g)[idx] != 0;
}

// ---------------------------------------------------------------------------
// Prep GEMV batch (grouped by position class), out-split x8 for TLP.
// grid = 3 tensors * 2 b * 34 row-chunks * 8 out-chunks = 1632.
// Wave w handles rows rg*4..rg*4+3; lane = one of 64 outputs (coalesced store).
__global__ __launch_bounds__(256) void prep_kernel(
    const float* __restrict__ Xq, const float* __restrict__ Xk, const float* __restrict__ Xv,
    const float* __restrict__ Wq, const float* __restrict__ Wk, const float* __restrict__ Wv,
    const float* __restrict__ Bq, const float* __restrict__ Bk, const float* __restrict__ Bv,
    float* __restrict__ Yq, float* __restrict__ Yk, float* __restrict__ Yv) {
  __shared__ float xs[16][HH];
  const int idx = blockIdx.x;
  const int oc = idx & 7;
  const int rem2 = idx >> 3;               // 0..203
  const int tb = rem2 / 34, rem = rem2 % 34;
  const int tensor = tb >> 1, b = tb & 1;
  int f, chunk;
  if (rem < 4)       { f = 0; chunk = rem; }
  else if (rem < 8)  { f = 1; chunk = rem - 4; }
  else if (rem < 12) { f = 2; chunk = rem - 8; }
  else if (rem < 23) { f = 3; chunk = rem - 12; }
  else               { f = 4; chunk = rem - 23; }
  const int count = (f < 3) ? 57 : 171;
  const float* X  = (tensor == 0) ? Xq : (tensor == 1) ? Xk : Xv;
  const float* W  = (tensor == 0) ? Wq : (tensor == 1) ? Wk : Wv;
  const float* Bi = (tensor == 0) ? Bq : (tensor == 1) ? Bk : Bv;
  float* Y        = (tensor == 0) ? Yq : (tensor == 1) ? Yk : Yv;
  const int tid = threadIdx.x;

  for (int r = 0; r < 16; ++r) {
    int i = chunk * 16 + r;
    if (i < count) {
      int t = (f < 3) ? (f + 9 * i) : (f + 2 * (i % 3) + 9 * (i / 3));
      const float* src = X + (size_t)(b * SS + t) * HH;
      xs[r][tid] = src[tid];
      xs[r][tid + 256] = src[tid + 256];
    }
  }
  __syncthreads();

  const int o = oc * 64 + (tid & 63);
  const int rg = tid >> 6;                  // wave index = row group
  const float* wrow = W + (size_t)f * HH * HH + (size_t)o * HH;
  float acc0 = 0.f, acc1 = 0.f, acc2 = 0.f, acc3 = 0.f;
  for (int hc = 0; hc < HH / 4; ++hc) {
    float4 w4 = *(const float4*)(wrow + hc * 4);
    acc0 += dot4(w4, *(const float4*)&xs[rg * 4 + 0][hc * 4]);
    acc1 += dot4(w4, *(const float4*)&xs[rg * 4 + 1][hc * 4]);
    acc2 += dot4(w4, *(const float4*)&xs[rg * 4 + 2][hc * 4]);
    acc3 += dot4(w4, *(const float4*)&xs[rg * 4 + 3][hc * 4]);
  }
  float bs = 0.f;
#pragma unroll
  for (int ff = 0; ff < 5; ++ff) bs += Bi[ff * HH + o];

  float accs[4] = {acc0, acc1, acc2, acc3};
#pragma unroll
  for (int j = 0; j < 4; ++j) {
    int i = chunk * 16 + rg * 4 + j;
    if (i < count) {
      int t = (f < 3) ? (f + 9 * i) : (f + 2 * (i % 3) + 9 * (i / 3));
      Y[(size_t)(b * SS + t) * HH + o] = accs[j] + bs;
    }
  }
}

// ---------------------------------------------------------------------------
// Partial V-sum over keys (for sparse all-masked rows).
__global__ __launch_bounds__(256) void vsum_part_kernel(const float* __restrict__ V,
                                                        float* __restrict__ part) {
  int idx = (blockIdx.x & 3) * 256 + threadIdx.x;
  int p = blockIdx.x >> 2;
  int b = idx >> 9, o = idx & 511;
  float acc = 0.f;
  for (int t = p; t < SS; t += 8)
    acc += V[(size_t)(b * SS + t) * HH + o];
  part[p * 1024 + idx] = acc;
}

// ---------------------------------------------------------------------------
// Sparse attention, q >= 3. One block per (b,q). Candidates {0,1,2,g,g+1}.
__global__ __launch_bounds__(256) void attn_sparse_kernel(
    const float* __restrict__ Q, const float* __restrict__ K, const float* __restrict__ V,
    const float* __restrict__ vsumPart, const void* __restrict__ graph,
    const int* __restrict__ flag,
    const float* __restrict__ EK, const float* __restrict__ EV, const float* __restrict__ EQ,
    float* __restrict__ X) {
  __shared__ float sQ[HH];
  __shared__ float sW[5 * NHH];
  __shared__ float sRed[4 * 64];
  __shared__ int sUni;

  const int tid = threadIdx.x, lane = tid & 63, wv = tid >> 6;
  const int bid = blockIdx.x;
  const int b = bid / 510, q = 3 + bid % 510;
  const int row = b * SS + q;
  const int isBool = *flag;

  sQ[tid] = Q[(size_t)row * HH + tid];
  sQ[tid + 256] = Q[(size_t)row * HH + tid + 256];
  if (tid == 0) sUni = 0;
  __syncthreads();

  const int g = 3 + ((q - 3) >> 1) * 2;
  const size_t gbase = (size_t)b * SS * SS + (size_t)q * SS;
  const int h = lane >> 3, dg = lane & 7, d0 = dg * 8;

  for (int c = wv; c < 5; c += 4) {
    int k = (c < 3) ? c : g + (c - 3);
    bool m = graph_at(graph, isBool, gbase + k);
    const float* ekp = EK + (gbase + k) * DDIM + d0;
    const float* eqp = EQ + ((size_t)(b * SS + k) * SS + q) * DDIM + d0;
    const float* kp  = K + (size_t)(b * SS + k) * HH + h * 64 + d0;
    const float* qp  = &sQ[h * 64 + d0];
    float4 ek0 = *(const float4*)ekp,      ek1 = *(const float4*)(ekp + 4);
    float4 eq0 = *(const float4*)eqp,      eq1 = *(const float4*)(eqp + 4);
    float4 kk0 = *(const float4*)kp,       kk1 = *(const float4*)(kp + 4);
    float4 qq0 = *(const float4*)qp,       qq1 = *(const float4*)(qp + 4);
    float p = dot4(add4(qq0, eq0), add4(kk0, ek0)) + dot4(add4(qq1, eq1), add4(kk1, ek1));
    p += __shfl_xor(p, 1);
    p += __shfl_xor(p, 2);
    p += __shfl_xor(p, 4);
    if (dg == 0) sW[c * NHH + h] = m ? p * 0.125f : -1e30f;
  }
  __syncthreads();

  if (wv == 0) {
    int hh = lane >> 3, c = lane & 7;
    float s = (c < 5) ? sW[c * NHH + hh] : -1e30f;
    float mx = s;
#pragma unroll
    for (int off = 4; off; off >>= 1) mx = fmaxf(mx, __shfl_xor(mx, off));
    float e = (mx < -1e29f) ? 0.f : __expf(s - mx);
    float sum = e;
#pragma unroll
    for (int off = 4; off; off >>= 1) sum += __shfl_xor(sum, off);
    if (c < 5) sW[c * NHH + hh] = (mx < -1e29f) ? 0.f : e / sum;
    if (lane == 0 && mx < -1e29f) sUni = 1;
  }
  __syncthreads();

  if (sUni) {
    float acc = 0.f;
    for (int k = wv; k < SS; k += 4)
      acc += EV[(gbase + k) * DDIM + lane];
    sRed[wv * 64 + lane] = acc;
    __syncthreads();
    if (tid < 64) sRed[tid] = sRed[tid] + sRed[64 + tid] + sRed[128 + tid] + sRed[192 + tid];
    __syncthreads();
    const float c0 = 1.0f / 513.0f;
    for (int o = tid; o < HH; o += 256) {
      float vs = 0.f;
#pragma unroll
      for (int p = 0; p < 8; ++p) vs += vsumPart[p * 1024 + b * HH + o];
      X[(size_t)row * HH + o] = (vs + sRed[o & 63]) * c0;
    }
  } else {
#pragma unroll
    for (int rep = 0; rep < 2; ++rep) {
      int o = tid + rep * 256;
      int hh = o >> 6, d = o & 63;
      float acc = 0.f;
#pragma unroll
      for (int c = 0; c < 5; ++c) {
        int k = (c < 3) ? c : g + (c - 3);
        acc += sW[c * NHH + hh] *
               (V[(size_t)(b * SS + k) * HH + o] + EV[(gbase + k) * DDIM + d]);
      }
      X[(size_t)row * HH + o] = acc;
    }
  }
}

// ---------------------------------------------------------------------------
// Dense D1: scores for q<3. grid = 48*17. Wave: 8 keys x 1 head, lane=(kk,dg).
__global__ __launch_bounds__(256) void dense_score_kernel(
    const float* __restrict__ Q, const float* __restrict__ K,
    const void* __restrict__ graph, const int* __restrict__ flag,
    const float* __restrict__ EK, const float* __restrict__ EQ,
    float* __restrict__ sWS) {
  const int bid = blockIdx.x;
  const int bqh = bid / 17, ks = bid % 17;
  const int b = bqh / 24, r = bqh % 24, q = r >> 3, hd = r & 7;
  const int tid = threadIdx.x, lane = tid & 63, wv = tid >> 6;
  const int kk = lane >> 3, dg = lane & 7, d0 = dg * 8;
  const int isBool = *flag;
  const int k = ks * 32 + wv * 8 + kk;
  const int kc = (k < SS) ? k : (SS - 1);
  const size_t gbase = (size_t)b * SS * SS + (size_t)q * SS;
  const bool m = (k < SS) && graph_at(graph, isBool, gbase + kc);

  const float* qp  = Q + (size_t)(b * SS + q) * HH + hd * 64 + d0;
  const float* ekp = EK + (gbase + kc) * DDIM + d0;
  const float* eqp = EQ + ((size_t)(b * SS + kc) * SS + q) * DDIM + d0;
  const float* kp  = K + (size_t)(b * SS + kc) * HH + hd * 64 + d0;
  float4 qq0 = *(const float4*)qp,  qq1 = *(const float4*)(qp + 4);
  float4 ek0 = *(const float4*)ekp, ek1 = *(const float4*)(ekp + 4);
  float4 eq0 = *(const float4*)eqp, eq1 = *(const float4*)(eqp + 4);
  float4 kk0 = *(const float4*)kp,  kk1 = *(const float4*)(kp + 4);
  float p = dot4(add4(qq0, eq0), add4(kk0, ek0)) + dot4(add4(qq1, eq1), add4(kk1, ek1));
  p += __shfl_xor(p, 1);
  p += __shfl_xor(p, 2);
  p += __shfl_xor(p, 4);
  if (dg == 0 && k < SS)
    sWS[(size_t)bqh * SS + k] = m ? p * 0.125f : -1e30f;
}

// ---------------------------------------------------------------------------
// Dense D2: softmax over 513 per (b,q,h), in place.
__global__ __launch_bounds__(256) void dense_softmax_kernel(float* __restrict__ sWS) {
  __shared__ float red[8];
  const int bqh = blockIdx.x;
  const int tid = threadIdx.x, lane = tid & 63, wv = tid >> 6;
  float* s = sWS + (size_t)bqh * SS;

  float mx = -3e38f;
  for (int k = tid; k < SS; k += 256) mx = fmaxf(mx, s[k]);
#pragma unroll
  for (int off = 32; off; off >>= 1) mx = fmaxf(mx, __shfl_xor(mx, off));
  if (lane == 0) red[wv] = mx;
  __syncthreads();
  mx = fmaxf(fmaxf(red[0], red[1]), fmaxf(red[2], red[3]));

  if (mx < -1e29f) {
    const float u = 1.0f / 513.0f;
    for (int k = tid; k < SS; k += 256) s[k] = u;
    return;
  }
  float sum = 0.f;
  for (int k = tid; k < SS; k += 256) sum += __expf(s[k] - mx);
#pragma unroll
  for (int off = 32; off; off >>= 1) sum += __shfl_xor(sum, off);
  if (lane == 0) red[4 + wv] = sum;
  __syncthreads();
  const float inv = 1.0f / (red[4] + red[5] + red[6] + red[7]);
  for (int k = tid; k < SS; k += 256) s[k] = __expf(s[k] - mx) * inv;
}

// ---------------------------------------------------------------------------
// Dense D3: partial weighted sums. grid = 48*8; block covers 65 keys.
__global__ __launch_bounds__(256) void dense_out_kernel(
    const float* __restrict__ V, const float* __restrict__ EV,
    const float* __restrict__ sWS, float* __restrict__ pOut) {
  __shared__ float sRed[4][DDIM];
  const int bqh = blockIdx.x >> 3, sl = blockIdx.x & 7;
  const int b = bqh / 24, r = bqh % 24, q = r >> 3, hd = r & 7;
  const int tid = threadIdx.x, lane = tid & 63, wv = tid >> 6;
  const size_t evbase = ((size_t)(b * SS + q) * SS) * DDIM;

  float acc = 0.f;
  for (int i = wv; i < 65; i += 4) {
    int k = sl * 65 + i;
    if (k < SS) {
      float w = sWS[(size_t)bqh * SS + k];
      acc += w * (V[(size_t)(b * SS + k) * HH + hd * 64 + lane] +
                  EV[evbase + (size_t)k * DDIM + lane]);
    }
  }
  sRed[wv][lane] = acc;
  __syncthreads();
  if (tid < 64)
    pOut[((size_t)bqh * 8 + sl) * DDIM + tid] =
        sRed[0][tid] + sRed[1][tid] + sRed[2][tid] + sRed[3][tid];
}

// ---------------------------------------------------------------------------
// Dense D4: combine 8 partials. grid = 48, block = 64.
__global__ __launch_bounds__(64) void dense_combine_kernel(
    const float* __restrict__ pOut, float* __restrict__ X) {
  const int bqh = blockIdx.x;
  const int b = bqh / 24, r = bqh % 24, q = r >> 3, hd = r & 7;
  const int d = threadIdx.x;
  float s = 0.f;
#pragma unroll
  for (int sl = 0; sl < 8; ++sl) s += pOut[((size_t)bqh * 8 + sl) * DDIM + d];
  X[(size_t)(b * SS + q) * HH + hd * 64 + d] = s;
}

// ---------------------------------------------------------------------------
// Output projection, out-split x8. grid = 65 row-chunks * 8 out-chunks = 520.
__global__ __launch_bounds__(256) void proj_kernel(const float* __restrict__ Xin,
                                                   const float* __restrict__ Wo,
                                                   const float* __restrict__ bo,
                                                   float* __restrict__ out) {
  __shared__ float xs[16][HH];
  const int chunk = blockIdx.x >> 3;
  const int oc = blockIdx.x & 7;
  const int tid = threadIdx.x;
  const int NROW = BB * SS;
  for (int r = 0; r < 16; ++r) {
    int row = chunk * 16 + r;
    if (row < NROW) {
      const float* src = Xin + (size_t)row * HH;
      xs[r][tid] = src[tid];
      xs[r][tid + 256] = src[tid + 256];
    }
  }
  __syncthreads();

  const int o = oc * 64 + (tid & 63);
  const int rg = tid >> 6;
  const float* w = Wo + (size_t)o * HH;
  float acc0 = 0.f, acc1 = 0.f, acc2 = 0.f, acc3 = 0.f;
  for (int hc = 0; hc < HH / 4; ++hc) {
    float4 w4 = *(const float4*)(w + hc * 4);
    acc0 += dot4(w4, *(const float4*)&xs[rg * 4 + 0][hc * 4]);
    acc1 += dot4(w4, *(const float4*)&xs[rg * 4 + 1][hc * 4]);
    acc2 += dot4(w4, *(const float4*)&xs[rg * 4 + 2][hc * 4]);
    acc3 += dot4(w4, *(const float4*)&xs[rg * 4 + 3][hc * 4]);
  }
  const float bias = bo[o];
  float accs[4] = {acc0, acc1, acc2, acc3};
#pragma unroll
  for (int j = 0; j < 4; ++j) {
    int row = chunk * 16 + rg * 4 + j;
    if (row < NROW) out[(size_t)row * HH + o] = accs[j] + bias;
  }
}

// ---------------------------------------------------------------------------
extern "C" void kernel_launch(void* const* d_in, const int* in_sizes, int n_in,
                              void* d_out, int out_size, void* d_ws, size_t ws_size,
                              hipStream_t stream) {
  (void)in_sizes; (void)n_in; (void)out_size; (void)ws_size;
  const float* query = (const float*)d_in[0];
  const float* key   = (const float*)d_in[1];
  const float* value = (const float*)d_in[2];
  const void*  graph = d_in[3];
  const float* EK = (const float*)d_in[4];
  const float* EV = (const float*)d_in[5];
  const float* EQ = (const float*)d_in[6];
  const float* Wq = (const float*)d_in[7];
  const float* bq = (const float*)d_in[8];
  const float* Wk = (const float*)d_in[9];
  const float* bk = (const float*)d_in[10];
  const float* Wv = (const float*)d_in[11];
  const float* bv = (const float*)d_in[12];
  const float* Wo = (const float*)d_in[13];
  const float* bo = (const float*)d_in[14];
  float* out = (float*)d_out;

  char* ws = (char*)d_ws;
  int*   flag = (int*)ws;                        // 4 B
  float* part = (float*)(ws + 256);              // 32 KB
  float* Qp = (float*)(ws + 40960);              // 2101248 B each
  float* Kp = (float*)(ws + 40960 + 2101248);
  float* Vp = (float*)(ws + 40960 + 2 * 2101248);
  float* Xp = (float*)(ws + 40960 + 3 * 2101248);
  float* sWS  = (float*)(ws + 40960 + 4 * 2101248);            // 98496 B
  float* pOut = (float*)(ws + 40960 + 4 * 2101248 + 98560);    // 98304 B

  detect_kernel<<<1, 256, 0, stream>>>((const uint4*)graph, flag);
  prep_kernel<<<1632, 256, 0, stream>>>(query, key, value, Wq, Wk, Wv, bq, bk, bv,
                                        Qp, Kp, Vp);
  vsum_part_kernel<<<32, 256, 0, stream>>>(Vp, part);
  attn_sparse_kernel<<<BB * (SS - 3), 256, 0, stream>>>(Qp, Kp, Vp, part, graph, flag,
                                                        EK, EV, EQ, Xp);
  dense_score_kernel<<<48 * 17, 256, 0, stream>>>(Qp, Kp, graph, flag, EK, EQ, sWS);
  dense_softmax_kernel<<<48, 256, 0, stream>>>(sWS);
  dense_out_kernel<<<48 * 8, 256, 0, stream>>>(Vp, EV, sWS, pOut);
  dense_combine_kernel<<<48, 64, 0, stream>>>(pOut, Xp);
  proj_kernel<<<520, 256, 0, stream>>>(Xp, Wo, bo, out);
}

// Round 5
// 195.652 us; speedup vs baseline: 1.2940x; 1.2940x over previous
//
#include <hip/hip_runtime.h>
#include <hip/hip_bf16.h>

#define BB 2
#define SS 513
#define HH 512
#define NHH 8
#define DDIM 64

__device__ __forceinline__ float dot4(float4 a, float4 b) {
  return a.x * b.x + a.y * b.y + a.z * b.z + a.w * b.w;
}
__device__ __forceinline__ float4 add4(float4 a, float4 b) {
  return make_float4(a.x + b.x, a.y + b.y, a.z + b.z, a.w + b.w);
}

// ---------------------------------------------------------------------------
// Detect graph buffer layout: bool (1B/elem) vs int32/float32 (4B/elem).
__global__ __launch_bounds__(256) void detect_kernel(const uint4* __restrict__ gv,
                                                     int* __restrict__ flag) {
  __shared__ int s;
  if (threadIdx.x == 0) s = 0;
  __syncthreads();
  unsigned int local = 0;
  for (int i = threadIdx.x; i < 2048; i += 256) {  // 32 KB scan
    uint4 v = gv[i];
    local |= (v.x | v.y | v.z | v.w) & 0x0000ff00u;
  }
  if (local) atomicOr(&s, 1);
  __syncthreads();
  if (threadIdx.x == 0) *flag = s;
}

__device__ __forceinline__ bool graph_at(const void* g, int isBool, size_t idx) {
  if (isBool) return ((const unsigned char*)g)[idx] != 0;
  return ((const int*)g)[idx] != 0;
}

// ---------------------------------------------------------------------------
// Prep GEMV, in-block K-split x4.
// grid = 3 tensors * 2 b * (3*8 + 2*22 = 68) row-chunks = 408, block = 1024.
// Thread: o = tid&255 (owns outputs o, o+256), kq = tid>>8 -> K-range kq*128.
// 8 rows/block staged in LDS (broadcast reads). Partials combined via LDS tree.
__global__ __launch_bounds__(1024) void prep_kernel(
    const float* __restrict__ Xq, const float* __restrict__ Xk, const float* __restrict__ Xv,
    const float* __restrict__ Wq, const float* __restrict__ Wk, const float* __restrict__ Wv,
    const float* __restrict__ Bq, const float* __restrict__ Bk, const float* __restrict__ Bv,
    float* __restrict__ Yq, float* __restrict__ Yk, float* __restrict__ Yv) {
  __shared__ float xs[8][HH];          // 16 KB
  __shared__ float ex[2][8][HH];       // 32 KB exchange

  const int bid = blockIdx.x;
  const int unit = bid % 68;
  const int tb = bid / 68;
  const int tensor = tb >> 1, b = tb & 1;
  int f, chunk, count;
  if (unit < 24) { f = unit >> 3; chunk = unit & 7; count = 57; }
  else           { int u = unit - 24; f = 3 + u / 22; chunk = u % 22; count = 171; }

  const float* X  = (tensor == 0) ? Xq : (tensor == 1) ? Xk : Xv;
  const float* W  = (tensor == 0) ? Wq : (tensor == 1) ? Wk : Wv;
  const float* Bi = (tensor == 0) ? Bq : (tensor == 1) ? Bk : Bv;
  float* Y        = (tensor == 0) ? Yq : (tensor == 1) ? Yk : Yv;

  const int tid = threadIdx.x;

  // stage 8 rows (one float4 per thread, coalesced)
  {
    const int r = tid >> 7, c = (tid & 127) << 2;
    const int i = chunk * 8 + r;
    if (i < count) {
      const int t = (f < 3) ? (f + 9 * i) : (f + 2 * (i % 3) + 9 * (i / 3));
      *(float4*)&xs[r][c] = *(const float4*)(X + (size_t)(b * SS + t) * HH + c);
    }
  }
  __syncthreads();

  const int o = tid & 255, kq = tid >> 8, k0 = kq * 128;
  const float* w0 = W + (size_t)f * HH * HH + (size_t)o * HH + k0;
  const float* w1 = w0 + 256 * HH;
  float acc0[8], acc1[8];
#pragma unroll
  for (int r = 0; r < 8; ++r) { acc0[r] = 0.f; acc1[r] = 0.f; }
  for (int hc = 0; hc < 32; ++hc) {
    float4 a = *(const float4*)(w0 + hc * 4);
    float4 c4 = *(const float4*)(w1 + hc * 4);
#pragma unroll
    for (int r = 0; r < 8; ++r) {
      float4 x4 = *(const float4*)&xs[r][k0 + hc * 4];
      acc0[r] += dot4(a, x4);
      acc1[r] += dot4(c4, x4);
    }
  }

  // combine tree: kq1->ex0, kq3->ex1 ; kq0+=ex0, kq2+=ex1 ; kq2->ex0 ; kq0+=ex0
  if (kq & 1) {
#pragma unroll
    for (int r = 0; r < 8; ++r) { ex[kq >> 1][r][o] = acc0[r]; ex[kq >> 1][r][o + 256] = acc1[r]; }
  }
  __syncthreads();
  if (!(kq & 1)) {
#pragma unroll
    for (int r = 0; r < 8; ++r) { acc0[r] += ex[kq >> 1][r][o]; acc1[r] += ex[kq >> 1][r][o + 256]; }
  }
  __syncthreads();
  if (kq == 2) {
#pragma unroll
    for (int r = 0; r < 8; ++r) { ex[0][r][o] = acc0[r]; ex[0][r][o + 256] = acc1[r]; }
  }
  __syncthreads();
  if (kq == 0) {
    float bs0 = 0.f, bs1 = 0.f;
#pragma unroll
    for (int ff = 0; ff < 5; ++ff) { bs0 += Bi[ff * HH + o]; bs1 += Bi[ff * HH + o + 256]; }
#pragma unroll
    for (int r = 0; r < 8; ++r) {
      int i = chunk * 8 + r;
      if (i < count) {
        int t = (f < 3) ? (f + 9 * i) : (f + 2 * (i % 3) + 9 * (i / 3));
        float* dst = Y + (size_t)(b * SS + t) * HH;
        dst[o]       = acc0[r] + ex[0][r][o]       + bs0;
        dst[o + 256] = acc1[r] + ex[0][r][o + 256] + bs1;
      }
    }
  }
}

// ---------------------------------------------------------------------------
// Partial V-sum over keys (for sparse all-masked rows).
__global__ __launch_bounds__(256) void vsum_part_kernel(const float* __restrict__ V,
                                                        float* __restrict__ part) {
  int idx = (blockIdx.x & 3) * 256 + threadIdx.x;
  int p = blockIdx.x >> 2;
  int b = idx >> 9, o = idx & 511;
  float acc = 0.f;
  for (int t = p; t < SS; t += 8)
    acc += V[(size_t)(b * SS + t) * HH + o];
  part[p * 1024 + idx] = acc;
}

// ---------------------------------------------------------------------------
// Sparse attention, q >= 3. One block per (b,q). Candidates {0,1,2,g,g+1}.
__global__ __launch_bounds__(256) void attn_sparse_kernel(
    const float* __restrict__ Q, const float* __restrict__ K, const float* __restrict__ V,
    const float* __restrict__ vsumPart, const void* __restrict__ graph,
    const int* __restrict__ flag,
    const float* __restrict__ EK, const float* __restrict__ EV, const float* __restrict__ EQ,
    float* __restrict__ X) {
  __shared__ float sQ[HH];
  __shared__ float sW[5 * NHH];
  __shared__ float sRed[4 * 64];
  __shared__ int sUni;

  const int tid = threadIdx.x, lane = tid & 63, wv = tid >> 6;
  const int bid = blockIdx.x;
  const int b = bid / 510, q = 3 + bid % 510;
  const int row = b * SS + q;
  const int isBool = *flag;

  sQ[tid] = Q[(size_t)row * HH + tid];
  sQ[tid + 256] = Q[(size_t)row * HH + tid + 256];
  if (tid == 0) sUni = 0;
  __syncthreads();

  const int g = 3 + ((q - 3) >> 1) * 2;
  const size_t gbase = (size_t)b * SS * SS + (size_t)q * SS;
  const int h = lane >> 3, dg = lane & 7, d0 = dg * 8;

  for (int c = wv; c < 5; c += 4) {
    int k = (c < 3) ? c : g + (c - 3);
    bool m = graph_at(graph, isBool, gbase + k);
    const float* ekp = EK + (gbase + k) * DDIM + d0;
    const float* eqp = EQ + ((size_t)(b * SS + k) * SS + q) * DDIM + d0;
    const float* kp  = K + (size_t)(b * SS + k) * HH + h * 64 + d0;
    const float* qp  = &sQ[h * 64 + d0];
    float4 ek0 = *(const float4*)ekp,      ek1 = *(const float4*)(ekp + 4);
    float4 eq0 = *(const float4*)eqp,      eq1 = *(const float4*)(eqp + 4);
    float4 kk0 = *(const float4*)kp,       kk1 = *(const float4*)(kp + 4);
    float4 qq0 = *(const float4*)qp,       qq1 = *(const float4*)(qp + 4);
    float p = dot4(add4(qq0, eq0), add4(kk0, ek0)) + dot4(add4(qq1, eq1), add4(kk1, ek1));
    p += __shfl_xor(p, 1);
    p += __shfl_xor(p, 2);
    p += __shfl_xor(p, 4);
    if (dg == 0) sW[c * NHH + h] = m ? p * 0.125f : -1e30f;
  }
  __syncthreads();

  if (wv == 0) {
    int hh = lane >> 3, c = lane & 7;
    float s = (c < 5) ? sW[c * NHH + hh] : -1e30f;
    float mx = s;
#pragma unroll
    for (int off = 4; off; off >>= 1) mx = fmaxf(mx, __shfl_xor(mx, off));
    float e = (mx < -1e29f) ? 0.f : __expf(s - mx);
    float sum = e;
#pragma unroll
    for (int off = 4; off; off >>= 1) sum += __shfl_xor(sum, off);
    if (c < 5) sW[c * NHH + hh] = (mx < -1e29f) ? 0.f : e / sum;
    if (lane == 0 && mx < -1e29f) sUni = 1;
  }
  __syncthreads();

  if (sUni) {
    float acc = 0.f;
    for (int k = wv; k < SS; k += 4)
      acc += EV[(gbase + k) * DDIM + lane];
    sRed[wv * 64 + lane] = acc;
    __syncthreads();
    if (tid < 64) sRed[tid] = sRed[tid] + sRed[64 + tid] + sRed[128 + tid] + sRed[192 + tid];
    __syncthreads();
    const float c0 = 1.0f / 513.0f;
    for (int o = tid; o < HH; o += 256) {
      float vs = 0.f;
#pragma unroll
      for (int p = 0; p < 8; ++p) vs += vsumPart[p * 1024 + b * HH + o];
      X[(size_t)row * HH + o] = (vs + sRed[o & 63]) * c0;
    }
  } else {
#pragma unroll
    for (int rep = 0; rep < 2; ++rep) {
      int o = tid + rep * 256;
      int hh = o >> 6, d = o & 63;
      float acc = 0.f;
#pragma unroll
      for (int c = 0; c < 5; ++c) {
        int k = (c < 3) ? c : g + (c - 3);
        acc += sW[c * NHH + hh] *
               (V[(size_t)(b * SS + k) * HH + o] + EV[(gbase + k) * DDIM + d]);
      }
      X[(size_t)row * HH + o] = acc;
    }
  }
}

// ---------------------------------------------------------------------------
// Dense D1: scores for q<3. grid = 48*17. Wave: 8 keys x 1 head, lane=(kk,dg).
__global__ __launch_bounds__(256) void dense_score_kernel(
    const float* __restrict__ Q, const float* __restrict__ K,
    const void* __restrict__ graph, const int* __restrict__ flag,
    const float* __restrict__ EK, const float* __restrict__ EQ,
    float* __restrict__ sWS) {
  const int bid = blockIdx.x;
  const int bqh = bid / 17, ks = bid % 17;
  const int b = bqh / 24, r = bqh % 24, q = r >> 3, hd = r & 7;
  const int tid = threadIdx.x, lane = tid & 63, wv = tid >> 6;
  const int kk = lane >> 3, dg = lane & 7, d0 = dg * 8;
  const int isBool = *flag;
  const int k = ks * 32 + wv * 8 + kk;
  const int kc = (k < SS) ? k : (SS - 1);
  const size_t gbase = (size_t)b * SS * SS + (size_t)q * SS;
  const bool m = (k < SS) && graph_at(graph, isBool, gbase + kc);

  const float* qp  = Q + (size_t)(b * SS + q) * HH + hd * 64 + d0;
  const float* ekp = EK + (gbase + kc) * DDIM + d0;
  const float* eqp = EQ + ((size_t)(b * SS + kc) * SS + q) * DDIM + d0;
  const float* kp  = K + (size_t)(b * SS + kc) * HH + hd * 64 + d0;
  float4 qq0 = *(const float4*)qp,  qq1 = *(const float4*)(qp + 4);
  float4 ek0 = *(const float4*)ekp, ek1 = *(const float4*)(ekp + 4);
  float4 eq0 = *(const float4*)eqp, eq1 = *(const float4*)(eqp + 4);
  float4 kk0 = *(const float4*)kp,  kk1 = *(const float4*)(kp + 4);
  float p = dot4(add4(qq0, eq0), add4(kk0, ek0)) + dot4(add4(qq1, eq1), add4(kk1, ek1));
  p += __shfl_xor(p, 1);
  p += __shfl_xor(p, 2);
  p += __shfl_xor(p, 4);
  if (dg == 0 && k < SS)
    sWS[(size_t)bqh * SS + k] = m ? p * 0.125f : -1e30f;
}

// ---------------------------------------------------------------------------
// Dense D2: softmax over 513 per (b,q,h), in place.
__global__ __launch_bounds__(256) void dense_softmax_kernel(float* __restrict__ sWS) {
  __shared__ float red[8];
  const int bqh = blockIdx.x;
  const int tid = threadIdx.x, lane = tid & 63, wv = tid >> 6;
  float* s = sWS + (size_t)bqh * SS;

  float mx = -3e38f;
  for (int k = tid; k < SS; k += 256) mx = fmaxf(mx, s[k]);
#pragma unroll
  for (int off = 32; off; off >>= 1) mx = fmaxf(mx, __shfl_xor(mx, off));
  if (lane == 0) red[wv] = mx;
  __syncthreads();
  mx = fmaxf(fmaxf(red[0], red[1]), fmaxf(red[2], red[3]));

  if (mx < -1e29f) {
    const float u = 1.0f / 513.0f;
    for (int k = tid; k < SS; k += 256) s[k] = u;
    return;
  }
  float sum = 0.f;
  for (int k = tid; k < SS; k += 256) sum += __expf(s[k] - mx);
#pragma unroll
  for (int off = 32; off; off >>= 1) sum += __shfl_xor(sum, off);
  if (lane == 0) red[4 + wv] = sum;
  __syncthreads();
  const float inv = 1.0f / (red[4] + red[5] + red[6] + red[7]);
  for (int k = tid; k < SS; k += 256) s[k] = __expf(s[k] - mx) * inv;
}

// ---------------------------------------------------------------------------
// Dense D3: partial weighted sums. grid = 48*8; block covers 65 keys.
__global__ __launch_bounds__(256) void dense_out_kernel(
    const float* __restrict__ V, const float* __restrict__ EV,
    const float* __restrict__ sWS, float* __restrict__ pOut) {
  __shared__ float sRed[4][DDIM];
  const int bqh = blockIdx.x >> 3, sl = blockIdx.x & 7;
  const int b = bqh / 24, r = bqh % 24, q = r >> 3, hd = r & 7;
  const int tid = threadIdx.x, lane = tid & 63, wv = tid >> 6;
  const size_t evbase = ((size_t)(b * SS + q) * SS) * DDIM;

  float acc = 0.f;
  for (int i = wv; i < 65; i += 4) {
    int k = sl * 65 + i;
    if (k < SS) {
      float w = sWS[(size_t)bqh * SS + k];
      acc += w * (V[(size_t)(b * SS + k) * HH + hd * 64 + lane] +
                  EV[evbase + (size_t)k * DDIM + lane]);
    }
  }
  sRed[wv][lane] = acc;
  __syncthreads();
  if (tid < 64)
    pOut[((size_t)bqh * 8 + sl) * DDIM + tid] =
        sRed[0][tid] + sRed[1][tid] + sRed[2][tid] + sRed[3][tid];
}

// ---------------------------------------------------------------------------
// Dense D4: combine 8 partials. grid = 48, block = 64.
__global__ __launch_bounds__(64) void dense_combine_kernel(
    const float* __restrict__ pOut, float* __restrict__ X) {
  const int bqh = blockIdx.x;
  const int b = bqh / 24, r = bqh % 24, q = r >> 3, hd = r & 7;
  const int d = threadIdx.x;
  float s = 0.f;
#pragma unroll
  for (int sl = 0; sl < 8; ++sl) s += pOut[((size_t)bqh * 8 + sl) * DDIM + d];
  X[(size_t)(b * SS + q) * HH + hd * 64 + d] = s;
}

// ---------------------------------------------------------------------------
// Output projection, in-block K-split x4.
// grid = 129 row-chunks(8) * 2 out-halves = 258, block = 1024.
// Thread: o = oc*256 + (tid&255), kq = tid>>8 -> K-range kq*128.
__global__ __launch_bounds__(1024) void proj_kernel(const float* __restrict__ Xin,
                                                    const float* __restrict__ Wo,
                                                    const float* __restrict__ bo,
                                                    float* __restrict__ out) {
  __shared__ float xs[8][HH];          // 16 KB
  __shared__ float ex[2][8][256];      // 16 KB

  const int chunk = blockIdx.x >> 1;
  const int oc = blockIdx.x & 1;
  const int tid = threadIdx.x;
  const int NROW = BB * SS;

  {
    const int r = tid >> 7, c = (tid & 127) << 2;
    const int row = chunk * 8 + r;
    if (row < NROW)
      *(float4*)&xs[r][c] = *(const float4*)(Xin + (size_t)row * HH + c);
  }
  __syncthreads();

  const int ol = tid & 255, o = oc * 256 + ol, kq = tid >> 8, k0 = kq * 128;
  const float* w = Wo + (size_t)o * HH + k0;
  float acc[8];
#pragma unroll
  for (int r = 0; r < 8; ++r) acc[r] = 0.f;
  for (int hc = 0; hc < 32; ++hc) {
    float4 w4 = *(const float4*)(w + hc * 4);
#pragma unroll
    for (int r = 0; r < 8; ++r)
      acc[r] += dot4(w4, *(const float4*)&xs[r][k0 + hc * 4]);
  }

  if (kq & 1) {
#pragma unroll
    for (int r = 0; r < 8; ++r) ex[kq >> 1][r][ol] = acc[r];
  }
  __syncthreads();
  if (!(kq & 1)) {
#pragma unroll
    for (int r = 0; r < 8; ++r) acc[r] += ex[kq >> 1][r][ol];
  }
  __syncthreads();
  if (kq == 2) {
#pragma unroll
    for (int r = 0; r < 8; ++r) ex[0][r][ol] = acc[r];
  }
  __syncthreads();
  if (kq == 0) {
    const float bias = bo[o];
#pragma unroll
    for (int r = 0; r < 8; ++r) {
      int row = chunk * 8 + r;
      if (row < NROW) out[(size_t)row * HH + o] = acc[r] + ex[0][r][ol] + bias;
    }
  }
}

// ---------------------------------------------------------------------------
extern "C" void kernel_launch(void* const* d_in, const int* in_sizes, int n_in,
                              void* d_out, int out_size, void* d_ws, size_t ws_size,
                              hipStream_t stream) {
  (void)in_sizes; (void)n_in; (void)out_size; (void)ws_size;
  const float* query = (const float*)d_in[0];
  const float* key   = (const float*)d_in[1];
  const float* value = (const float*)d_in[2];
  const void*  graph = d_in[3];
  const float* EK = (const float*)d_in[4];
  const float* EV = (const float*)d_in[5];
  const float* EQ = (const float*)d_in[6];
  const float* Wq = (const float*)d_in[7];
  const float* bq = (const float*)d_in[8];
  const float* Wk = (const float*)d_in[9];
  const float* bk = (const float*)d_in[10];
  const float* Wv = (const float*)d_in[11];
  const float* bv = (const float*)d_in[12];
  const float* Wo = (const float*)d_in[13];
  const float* bo = (const float*)d_in[14];
  float* out = (float*)d_out;

  char* ws = (char*)d_ws;
  int*   flag = (int*)ws;                        // 4 B
  float* part = (float*)(ws + 256);              // 32 KB
  float* Qp = (float*)(ws + 40960);              // 2101248 B each
  float* Kp = (float*)(ws + 40960 + 2101248);
  float* Vp = (float*)(ws + 40960 + 2 * 2101248);
  float* Xp = (float*)(ws + 40960 + 3 * 2101248);
  float* sWS  = (float*)(ws + 40960 + 4 * 2101248);            // 98496 B
  float* pOut = (float*)(ws + 40960 + 4 * 2101248 + 98560);    // 98304 B

  detect_kernel<<<1, 256, 0, stream>>>((const uint4*)graph, flag);
  prep_kernel<<<408, 1024, 0, stream>>>(query, key, value, Wq, Wk, Wv, bq, bk, bv,
                                        Qp, Kp, Vp);
  vsum_part_kernel<<<32, 256, 0, stream>>>(Vp, part);
  attn_sparse_kernel<<<BB * (SS - 3), 256, 0, stream>>>(Qp, Kp, Vp, part, graph, flag,
                                                        EK, EV, EQ, Xp);
  dense_score_kernel<<<48 * 17, 256, 0, stream>>>(Qp, Kp, graph, flag, EK, EQ, sWS);
  dense_softmax_kernel<<<48, 256, 0, stream>>>(sWS);
  dense_out_kernel<<<48 * 8, 256, 0, stream>>>(Vp, EV, sWS, pOut);
  dense_combine_kernel<<<48, 64, 0, stream>>>(pOut, Xp);
  proj_kernel<<<258, 1024, 0, stream>>>(Xp, Wo, bo, out);
}

// Round 6
// 155.150 us; speedup vs baseline: 1.6318x; 1.2611x over previous
//
#include <hip/hip_runtime.h>
#include <hip/hip_bf16.h>

#define BB 2
#define SS 513
#define HH 512
#define NHH 8
#define DDIM 64

__device__ __forceinline__ float dot4(float4 a, float4 b) {
  return a.x * b.x + a.y * b.y + a.z * b.z + a.w * b.w;
}
__device__ __forceinline__ float4 add4(float4 a, float4 b) {
  return make_float4(a.x + b.x, a.y + b.y, a.z + b.z, a.w + b.w);
}

// ---------------------------------------------------------------------------
// Detect graph buffer layout: bool (1B/elem) vs int32/float32 (4B/elem).
__global__ __launch_bounds__(256) void detect_kernel(const uint4* __restrict__ gv,
                                                     int* __restrict__ flag) {
  __shared__ int s;
  if (threadIdx.x == 0) s = 0;
  __syncthreads();
  unsigned int local = 0;
  for (int i = threadIdx.x; i < 2048; i += 256) {  // 32 KB scan
    uint4 v = gv[i];
    local |= (v.x | v.y | v.z | v.w) & 0x0000ff00u;
  }
  if (local) atomicOr(&s, 1);
  __syncthreads();
  if (threadIdx.x == 0) *flag = s;
}

__device__ __forceinline__ bool graph_at(const void* g, int isBool, size_t idx) {
  if (isBool) return ((const unsigned char*)g)[idx] != 0;
  return ((const int*)g)[idx] != 0;
}

// ---------------------------------------------------------------------------
// Prep GEMV, wave-coalesced W reads.
// grid = 3 tensors * 2 b * 68 row-chunks(8) = 408, block = 1024 (16 waves).
// Wave: 32 outputs in 4 batches of 8. lane = (og = lane>>3, kg = lane&7).
// Load i: W[o0+og][kg*4 + i*32] -> 8 lanes x 16B consecutive per og-group.
// Partial dot over kg reduced with 3 shfl_xor; kg==0 stores.
__global__ __launch_bounds__(1024) void prep_kernel(
    const float* __restrict__ Xq, const float* __restrict__ Xk, const float* __restrict__ Xv,
    const float* __restrict__ Wq, const float* __restrict__ Wk, const float* __restrict__ Wv,
    const float* __restrict__ Bq, const float* __restrict__ Bk, const float* __restrict__ Bv,
    float* __restrict__ Yq, float* __restrict__ Yk, float* __restrict__ Yv) {
  __shared__ float xs[8][HH];          // 16 KB

  const int bid = blockIdx.x;
  const int unit = bid % 68;
  const int tb = bid / 68;
  const int tensor = tb >> 1, b = tb & 1;
  int f, chunk, count;
  if (unit < 24) { f = unit >> 3; chunk = unit & 7; count = 57; }
  else           { int u = unit - 24; f = 3 + u / 22; chunk = u % 22; count = 171; }

  const float* X  = (tensor == 0) ? Xq : (tensor == 1) ? Xk : Xv;
  const float* W  = (tensor == 0) ? Wq : (tensor == 1) ? Wk : Wv;
  const float* Bi = (tensor == 0) ? Bq : (tensor == 1) ? Bk : Bv;
  float* Y        = (tensor == 0) ? Yq : (tensor == 1) ? Yk : Yv;

  const int tid = threadIdx.x;

  // stage 8 rows (one float4 per thread, coalesced)
  {
    const int r = tid >> 7, c = (tid & 127) << 2;
    const int i = chunk * 8 + r;
    if (i < count) {
      const int t = (f < 3) ? (f + 9 * i) : (f + 2 * (i % 3) + 9 * (i / 3));
      *(float4*)&xs[r][c] = *(const float4*)(X + (size_t)(b * SS + t) * HH + c);
    }
  }
  __syncthreads();

  const int wid = tid >> 6, lane = tid & 63;
  const int og = lane >> 3, kg = lane & 7;
  const float* Wf = W + (size_t)f * HH * HH;

#pragma unroll
  for (int batch = 0; batch < 4; ++batch) {
    const int o = wid * 32 + batch * 8 + og;
    const float* wrow = Wf + (size_t)o * HH + kg * 4;
    float acc[8];
#pragma unroll
    for (int r = 0; r < 8; ++r) acc[r] = 0.f;
#pragma unroll
    for (int i = 0; i < 16; ++i) {
      float4 w4 = *(const float4*)(wrow + i * 32);
#pragma unroll
      for (int r = 0; r < 8; ++r)
        acc[r] += dot4(w4, *(const float4*)&xs[r][kg * 4 + i * 32]);
    }
#pragma unroll
    for (int r = 0; r < 8; ++r) {
      acc[r] += __shfl_xor(acc[r], 1);
      acc[r] += __shfl_xor(acc[r], 2);
      acc[r] += __shfl_xor(acc[r], 4);
    }
    if (kg == 0) {
      float bs = 0.f;
#pragma unroll
      for (int ff = 0; ff < 5; ++ff) bs += Bi[ff * HH + o];
#pragma unroll
      for (int r = 0; r < 8; ++r) {
        int i = chunk * 8 + r;
        if (i < count) {
          int t = (f < 3) ? (f + 9 * i) : (f + 2 * (i % 3) + 9 * (i / 3));
          Y[(size_t)(b * SS + t) * HH + o] = acc[r] + bs;
        }
      }
    }
  }
}

// ---------------------------------------------------------------------------
// Partial V-sum over keys (for sparse all-masked rows).
__global__ __launch_bounds__(256) void vsum_part_kernel(const float* __restrict__ V,
                                                        float* __restrict__ part) {
  int idx = (blockIdx.x & 3) * 256 + threadIdx.x;
  int p = blockIdx.x >> 2;
  int b = idx >> 9, o = idx & 511;
  float acc = 0.f;
  for (int t = p; t < SS; t += 8)
    acc += V[(size_t)(b * SS + t) * HH + o];
  part[p * 1024 + idx] = acc;
}

// ---------------------------------------------------------------------------
// Sparse attention, q >= 3. One block per (b,q). Candidates {0,1,2,g,g+1}.
__global__ __launch_bounds__(256) void attn_sparse_kernel(
    const float* __restrict__ Q, const float* __restrict__ K, const float* __restrict__ V,
    const float* __restrict__ vsumPart, const void* __restrict__ graph,
    const int* __restrict__ flag,
    const float* __restrict__ EK, const float* __restrict__ EV, const float* __restrict__ EQ,
    float* __restrict__ X) {
  __shared__ float sQ[HH];
  __shared__ float sW[5 * NHH];
  __shared__ float sRed[4 * 64];
  __shared__ int sUni;

  const int tid = threadIdx.x, lane = tid & 63, wv = tid >> 6;
  const int bid = blockIdx.x;
  const int b = bid / 510, q = 3 + bid % 510;
  const int row = b * SS + q;
  const int isBool = *flag;

  sQ[tid] = Q[(size_t)row * HH + tid];
  sQ[tid + 256] = Q[(size_t)row * HH + tid + 256];
  if (tid == 0) sUni = 0;
  __syncthreads();

  const int g = 3 + ((q - 3) >> 1) * 2;
  const size_t gbase = (size_t)b * SS * SS + (size_t)q * SS;
  const int h = lane >> 3, dg = lane & 7, d0 = dg * 8;

  for (int c = wv; c < 5; c += 4) {
    int k = (c < 3) ? c : g + (c - 3);
    bool m = graph_at(graph, isBool, gbase + k);
    const float* ekp = EK + (gbase + k) * DDIM + d0;
    const float* eqp = EQ + ((size_t)(b * SS + k) * SS + q) * DDIM + d0;
    const float* kp  = K + (size_t)(b * SS + k) * HH + h * 64 + d0;
    const float* qp  = &sQ[h * 64 + d0];
    float4 ek0 = *(const float4*)ekp,      ek1 = *(const float4*)(ekp + 4);
    float4 eq0 = *(const float4*)eqp,      eq1 = *(const float4*)(eqp + 4);
    float4 kk0 = *(const float4*)kp,       kk1 = *(const float4*)(kp + 4);
    float4 qq0 = *(const float4*)qp,       qq1 = *(const float4*)(qp + 4);
    float p = dot4(add4(qq0, eq0), add4(kk0, ek0)) + dot4(add4(qq1, eq1), add4(kk1, ek1));
    p += __shfl_xor(p, 1);
    p += __shfl_xor(p, 2);
    p += __shfl_xor(p, 4);
    if (dg == 0) sW[c * NHH + h] = m ? p * 0.125f : -1e30f;
  }
  __syncthreads();

  if (wv == 0) {
    int hh = lane >> 3, c = lane & 7;
    float s = (c < 5) ? sW[c * NHH + hh] : -1e30f;
    float mx = s;
#pragma unroll
    for (int off = 4; off; off >>= 1) mx = fmaxf(mx, __shfl_xor(mx, off));
    float e = (mx < -1e29f) ? 0.f : __expf(s - mx);
    float sum = e;
#pragma unroll
    for (int off = 4; off; off >>= 1) sum += __shfl_xor(sum, off);
    if (c < 5) sW[c * NHH + hh] = (mx < -1e29f) ? 0.f : e / sum;
    if (lane == 0 && mx < -1e29f) sUni = 1;
  }
  __syncthreads();

  if (sUni) {
    float acc = 0.f;
    for (int k = wv; k < SS; k += 4)
      acc += EV[(gbase + k) * DDIM + lane];
    sRed[wv * 64 + lane] = acc;
    __syncthreads();
    if (tid < 64) sRed[tid] = sRed[tid] + sRed[64 + tid] + sRed[128 + tid] + sRed[192 + tid];
    __syncthreads();
    const float c0 = 1.0f / 513.0f;
    for (int o = tid; o < HH; o += 256) {
      float vs = 0.f;
#pragma unroll
      for (int p = 0; p < 8; ++p) vs += vsumPart[p * 1024 + b * HH + o];
      X[(size_t)row * HH + o] = (vs + sRed[o & 63]) * c0;
    }
  } else {
#pragma unroll
    for (int rep = 0; rep < 2; ++rep) {
      int o = tid + rep * 256;
      int hh = o >> 6, d = o & 63;
      float acc = 0.f;
#pragma unroll
      for (int c = 0; c < 5; ++c) {
        int k = (c < 3) ? c : g + (c - 3);
        acc += sW[c * NHH + hh] *
               (V[(size_t)(b * SS + k) * HH + o] + EV[(gbase + k) * DDIM + d]);
      }
      X[(size_t)row * HH + o] = acc;
    }
  }
}

// ---------------------------------------------------------------------------
// Dense D1: scores for q<3. grid = 48*17. Wave: 8 keys x 1 head, lane=(kk,dg).
__global__ __launch_bounds__(256) void dense_score_kernel(
    const float* __restrict__ Q, const float* __restrict__ K,
    const void* __restrict__ graph, const int* __restrict__ flag,
    const float* __restrict__ EK, const float* __restrict__ EQ,
    float* __restrict__ sWS) {
  const int bid = blockIdx.x;
  const int bqh = bid / 17, ks = bid % 17;
  const int b = bqh / 24, r = bqh % 24, q = r >> 3, hd = r & 7;
  const int tid = threadIdx.x, lane = tid & 63, wv = tid >> 6;
  const int kk = lane >> 3, dg = lane & 7, d0 = dg * 8;
  const int isBool = *flag;
  const int k = ks * 32 + wv * 8 + kk;
  const int kc = (k < SS) ? k : (SS - 1);
  const size_t gbase = (size_t)b * SS * SS + (size_t)q * SS;
  const bool m = (k < SS) && graph_at(graph, isBool, gbase + kc);

  const float* qp  = Q + (size_t)(b * SS + q) * HH + hd * 64 + d0;
  const float* ekp = EK + (gbase + kc) * DDIM + d0;
  const float* eqp = EQ + ((size_t)(b * SS + kc) * SS + q) * DDIM + d0;
  const float* kp  = K + (size_t)(b * SS + kc) * HH + hd * 64 + d0;
  float4 qq0 = *(const float4*)qp,  qq1 = *(const float4*)(qp + 4);
  float4 ek0 = *(const float4*)ekp, ek1 = *(const float4*)(ekp + 4);
  float4 eq0 = *(const float4*)eqp, eq1 = *(const float4*)(eqp + 4);
  float4 kk0 = *(const float4*)kp,  kk1 = *(const float4*)(kp + 4);
  float p = dot4(add4(qq0, eq0), add4(kk0, ek0)) + dot4(add4(qq1, eq1), add4(kk1, ek1));
  p += __shfl_xor(p, 1);
  p += __shfl_xor(p, 2);
  p += __shfl_xor(p, 4);
  if (dg == 0 && k < SS)
    sWS[(size_t)bqh * SS + k] = m ? p * 0.125f : -1e30f;
}

// ---------------------------------------------------------------------------
// Dense D2: softmax over 513 per (b,q,h), in place.
__global__ __launch_bounds__(256) void dense_softmax_kernel(float* __restrict__ sWS) {
  __shared__ float red[8];
  const int bqh = blockIdx.x;
  const int tid = threadIdx.x, lane = tid & 63, wv = tid >> 6;
  float* s = sWS + (size_t)bqh * SS;

  float mx = -3e38f;
  for (int k = tid; k < SS; k += 256) mx = fmaxf(mx, s[k]);
#pragma unroll
  for (int off = 32; off; off >>= 1) mx = fmaxf(mx, __shfl_xor(mx, off));
  if (lane == 0) red[wv] = mx;
  __syncthreads();
  mx = fmaxf(fmaxf(red[0], red[1]), fmaxf(red[2], red[3]));

  if (mx < -1e29f) {
    const float u = 1.0f / 513.0f;
    for (int k = tid; k < SS; k += 256) s[k] = u;
    return;
  }
  float sum = 0.f;
  for (int k = tid; k < SS; k += 256) sum += __expf(s[k] - mx);
#pragma unroll
  for (int off = 32; off; off >>= 1) sum += __shfl_xor(sum, off);
  if (lane == 0) red[4 + wv] = sum;
  __syncthreads();
  const float inv = 1.0f / (red[4] + red[5] + red[6] + red[7]);
  for (int k = tid; k < SS; k += 256) s[k] = __expf(s[k] - mx) * inv;
}

// ---------------------------------------------------------------------------
// Dense D3: partial weighted sums. grid = 48*8; block covers 65 keys.
__global__ __launch_bounds__(256) void dense_out_kernel(
    const float* __restrict__ V, const float* __restrict__ EV,
    const float* __restrict__ sWS, float* __restrict__ pOut) {
  __shared__ float sRed[4][DDIM];
  const int bqh = blockIdx.x >> 3, sl = blockIdx.x & 7;
  const int b = bqh / 24, r = bqh % 24, q = r >> 3, hd = r & 7;
  const int tid = threadIdx.x, lane = tid & 63, wv = tid >> 6;
  const size_t evbase = ((size_t)(b * SS + q) * SS) * DDIM;

  float acc = 0.f;
  for (int i = wv; i < 65; i += 4) {
    int k = sl * 65 + i;
    if (k < SS) {
      float w = sWS[(size_t)bqh * SS + k];
      acc += w * (V[(size_t)(b * SS + k) * HH + hd * 64 + lane] +
                  EV[evbase + (size_t)k * DDIM + lane]);
    }
  }
  sRed[wv][lane] = acc;
  __syncthreads();
  if (tid < 64)
    pOut[((size_t)bqh * 8 + sl) * DDIM + tid] =
        sRed[0][tid] + sRed[1][tid] + sRed[2][tid] + sRed[3][tid];
}

// ---------------------------------------------------------------------------
// Dense D4: combine 8 partials. grid = 48, block = 64.
__global__ __launch_bounds__(64) void dense_combine_kernel(
    const float* __restrict__ pOut, float* __restrict__ X) {
  const int bqh = blockIdx.x;
  const int b = bqh / 24, r = bqh % 24, q = r >> 3, hd = r & 7;
  const int d = threadIdx.x;
  float s = 0.f;
#pragma unroll
  for (int sl = 0; sl < 8; ++sl) s += pOut[((size_t)bqh * 8 + sl) * DDIM + d];
  X[(size_t)(b * SS + q) * HH + hd * 64 + d] = s;
}

// ---------------------------------------------------------------------------
// Output projection, wave-coalesced. grid = 129 chunks * 2 out-halves = 258,
// block = 1024 (16 waves). Each block: 8 rows staged, 256 outputs.
__global__ __launch_bounds__(1024) void proj_kernel(const float* __restrict__ Xin,
                                                    const float* __restrict__ Wo,
                                                    const float* __restrict__ bo,
                                                    float* __restrict__ out) {
  __shared__ float xs[8][HH];          // 16 KB

  const int chunk = blockIdx.x >> 1;
  const int oc = blockIdx.x & 1;
  const int tid = threadIdx.x;
  const int NROW = BB * SS;

  {
    const int r = tid >> 7, c = (tid & 127) << 2;
    const int row = chunk * 8 + r;
    if (row < NROW)
      *(float4*)&xs[r][c] = *(const float4*)(Xin + (size_t)row * HH + c);
  }
  __syncthreads();

  const int wid = tid >> 6, lane = tid & 63;
  const int og = lane >> 3, kg = lane & 7;

#pragma unroll
  for (int batch = 0; batch < 2; ++batch) {
    const int o = oc * 256 + wid * 16 + batch * 8 + og;
    const float* wrow = Wo + (size_t)o * HH + kg * 4;
    float acc[8];
#pragma unroll
    for (int r = 0; r < 8; ++r) acc[r] = 0.f;
#pragma unroll
    for (int i = 0; i < 16; ++i) {
      float4 w4 = *(const float4*)(wrow + i * 32);
#pragma unroll
      for (int r = 0; r < 8; ++r)
        acc[r] += dot4(w4, *(const float4*)&xs[r][kg * 4 + i * 32]);
    }
#pragma unroll
    for (int r = 0; r < 8; ++r) {
      acc[r] += __shfl_xor(acc[r], 1);
      acc[r] += __shfl_xor(acc[r], 2);
      acc[r] += __shfl_xor(acc[r], 4);
    }
    if (kg == 0) {
      const float bias = bo[o];
#pragma unroll
      for (int r = 0; r < 8; ++r) {
        int row = chunk * 8 + r;
        if (row < NROW) out[(size_t)row * HH + o] = acc[r] + bias;
      }
    }
  }
}

// ---------------------------------------------------------------------------
extern "C" void kernel_launch(void* const* d_in, const int* in_sizes, int n_in,
                              void* d_out, int out_size, void* d_ws, size_t ws_size,
                              hipStream_t stream) {
  (void)in_sizes; (void)n_in; (void)out_size; (void)ws_size;
  const float* query = (const float*)d_in[0];
  const float* key   = (const float*)d_in[1];
  const float* value = (const float*)d_in[2];
  const void*  graph = d_in[3];
  const float* EK = (const float*)d_in[4];
  const float* EV = (const float*)d_in[5];
  const float* EQ = (const float*)d_in[6];
  const float* Wq = (const float*)d_in[7];
  const float* bq = (const float*)d_in[8];
  const float* Wk = (const float*)d_in[9];
  const float* bk = (const float*)d_in[10];
  const float* Wv = (const float*)d_in[11];
  const float* bv = (const float*)d_in[12];
  const float* Wo = (const float*)d_in[13];
  const float* bo = (const float*)d_in[14];
  float* out = (float*)d_out;

  char* ws = (char*)d_ws;
  int*   flag = (int*)ws;                        // 4 B
  float* part = (float*)(ws + 256);              // 32 KB
  float* Qp = (float*)(ws + 40960);              // 2101248 B each
  float* Kp = (float*)(ws + 40960 + 2101248);
  float* Vp = (float*)(ws + 40960 + 2 * 2101248);
  float* Xp = (float*)(ws + 40960 + 3 * 2101248);
  float* sWS  = (float*)(ws + 40960 + 4 * 2101248);            // 98496 B
  float* pOut = (float*)(ws + 40960 + 4 * 2101248 + 98560);    // 98304 B

  detect_kernel<<<1, 256, 0, stream>>>((const uint4*)graph, flag);
  prep_kernel<<<408, 1024, 0, stream>>>(query, key, value, Wq, Wk, Wv, bq, bk, bv,
                                        Qp, Kp, Vp);
  vsum_part_kernel<<<32, 256, 0, stream>>>(Vp, part);
  attn_sparse_kernel<<<BB * (SS - 3), 256, 0, stream>>>(Qp, Kp, Vp, part, graph, flag,
                                                        EK, EV, EQ, Xp);
  dense_score_kernel<<<48 * 17, 256, 0, stream>>>(Qp, Kp, graph, flag, EK, EQ, sWS);
  dense_softmax_kernel<<<48, 256, 0, stream>>>(sWS);
  dense_out_kernel<<<48 * 8, 256, 0, stream>>>(Vp, EV, sWS, pOut);
  dense_combine_kernel<<<48, 64, 0, stream>>>(pOut, Xp);
  proj_kernel<<<258, 1024, 0, stream>>>(Xp, Wo, bo, out);
}